// Round 9
// baseline (624.586 us; speedup 1.0000x reference)
//
#include <hip/hip_runtime.h>
#include <math.h>

#define CH_IN   512
#define CH_OUT  256
#define HWD     4096
#define BATCH   32
#define MAXSLOT 32   // ptr can never exceed 32: at most one append per batch step

typedef __attribute__((ext_vector_type(8))) short short8;
typedef __attribute__((ext_vector_type(4))) float floatx4;

// fp32 -> bf16 RNE, packed pair into one uint (low = a, high = b)
__device__ __forceinline__ unsigned int pk_bf16(float a, float b) {
    unsigned int ua = __float_as_uint(a);
    ua += 0x7fffu + ((ua >> 16) & 1u);
    unsigned int ub = __float_as_uint(b);
    ub += 0x7fffu + ((ub >> 16) & 1u);
    return (ua >> 16) | (ub & 0xffff0000u);
}

// ---------------------------------------------------------------------------
// Kernel 1: proj = W @ feats + b  via bf16 MFMA 16x16x32, fp32 accumulate.
// Block: 256 thr = 4 waves (2x2), tile 128o x 128l, BK=64 (8 iters, 16 barriers
// vs 32: halves exposed-latency windows, doubles loads in flight per window).
// __launch_bounds__(256,4) pins VGPR <= 128 so occupancy stays 4 blocks/CU.
// Grid: 2048 linear, XCD-aware decode: the two ot-blocks of a (lt,b) tile
// occupy consecutive slots of the SAME XCD -> second feats read is an L2 hit.
// LDS: As[o][c] pitch 72 bf16 (2-way frag reads), Bs[l][c] pitch 74 (stride 37
// words coprime 32 -> conflict-free b32 frag reads). 37.4 KB -> 4 blocks/CU.
// K-chunk order per accumulator unchanged vs BK=32 -> bitwise-identical proj.
// Fused: pooled[b][o] += sum_l proj*preds (mean applied in k2).
// ---------------------------------------------------------------------------
#define PA2 72
#define PB2 74
__global__ __launch_bounds__(256, 4) void k1_proj_gemm(
    const float* __restrict__ feats, const float* __restrict__ preds,
    const float* __restrict__ W, const float* __restrict__ bias,
    float* __restrict__ out, float* __restrict__ pooled)
{
    __shared__ __align__(16) unsigned short As[128 * PA2];   // 18432 B
    __shared__ __align__(16) unsigned short Bs[128 * PB2];   // 18944 B

    const int t  = threadIdx.x;
    // XCD-aware decode: xcd = bid%8 (round-robin mapping), 256 slots per XCD.
    // tile = xcd*128 + slot/2, ot = slot%2  -> ot-pair adjacent on one XCD.
    const int bid  = blockIdx.x;
    const int xcd  = bid & 7;
    const int slot = bid >> 3;                 // 0..255
    const int tile = xcd * 128 + (slot >> 1);  // 0..1023
    const int ot   = slot & 1;
    const int lt   = tile & 31;
    const int b    = tile >> 5;

    const int l0 = lt * 128, o0 = ot * 128;
    const int lane = t & 63, wid = t >> 6;
    const int wm = wid & 1, wn = wid >> 1;       // wave 2x2 grid
    const int ln = lane & 15, quad = lane >> 4;

    floatx4 acc[4][4];
    #pragma unroll
    for (int i = 0; i < 4; i++)
        #pragma unroll
        for (int j = 0; j < 4; j++) acc[i][j] = (floatx4){0.f, 0.f, 0.f, 0.f};

    const float* Wb = W + (size_t)o0 * CH_IN;
    const float* Fb = feats + (size_t)b * CH_IN * HWD + l0;

    // B staging mapping: thread owns 8c x 4l micro-block
    const int l4 = t & 31;      // l = l4*4 + i
    const int cg = t >> 5;      // c = cg*8 + j

    #pragma unroll 1
    for (int k0 = 0; k0 < CH_IN; k0 += 64) {
        // ---- stage A: W tile 128o x 64c ----
        #pragma unroll
        for (int q = 0; q < 8; q++) {
            int idx = t + 256 * q;
            int o = idx >> 4, c4 = idx & 15;
            float4 w = *(const float4*)(Wb + (size_t)o * CH_IN + k0 + c4 * 4);
            unsigned int u0 = pk_bf16(w.x, w.y);
            unsigned int u1 = pk_bf16(w.z, w.w);
            *(uint2*)(As + o * PA2 + c4 * 4) = make_uint2(u0, u1);
        }
        // ---- stage B: feats tile 64c x 128l, transposed to Bs[l][c] ----
        float4 f[8];
        #pragma unroll
        for (int j = 0; j < 8; j++)
            f[j] = *(const float4*)(Fb + (size_t)(k0 + cg * 8 + j) * HWD + l4 * 4);
        {
            const float v0[4] = {f[0].x, f[0].y, f[0].z, f[0].w};
            const float v1[4] = {f[1].x, f[1].y, f[1].z, f[1].w};
            const float v2[4] = {f[2].x, f[2].y, f[2].z, f[2].w};
            const float v3[4] = {f[3].x, f[3].y, f[3].z, f[3].w};
            const float v4[4] = {f[4].x, f[4].y, f[4].z, f[4].w};
            const float v5[4] = {f[5].x, f[5].y, f[5].z, f[5].w};
            const float v6[4] = {f[6].x, f[6].y, f[6].z, f[6].w};
            const float v7[4] = {f[7].x, f[7].y, f[7].z, f[7].w};
            #pragma unroll
            for (int i = 0; i < 4; i++) {
                unsigned short* row = Bs + (l4 * 4 + i) * PB2 + cg * 8;
                *(unsigned int*)(row)     = pk_bf16(v0[i], v1[i]);
                *(unsigned int*)(row + 2) = pk_bf16(v2[i], v3[i]);
                *(unsigned int*)(row + 4) = pk_bf16(v4[i], v5[i]);
                *(unsigned int*)(row + 6) = pk_bf16(v6[i], v7[i]);
            }
        }
        __syncthreads();

        // ---- fragments + MFMA, two K=32 sub-steps (same acc order as BK=32) ----
        #pragma unroll
        for (int kk = 0; kk < 2; kk++) {
            short8 af[4], bf[4];
            #pragma unroll
            for (int mt = 0; mt < 4; mt++) {
                int row = wm * 64 + mt * 16 + ln;
                af[mt] = *(const short8*)(As + row * PA2 + kk * 32 + quad * 8);
            }
            #pragma unroll
            for (int nt = 0; nt < 4; nt++) {
                int row = wn * 64 + nt * 16 + ln;
                const unsigned short* p = Bs + row * PB2 + kk * 32 + quad * 8;
                union { short8 v; unsigned int u[4]; } r;
                r.u[0] = *(const unsigned int*)(p);
                r.u[1] = *(const unsigned int*)(p + 2);
                r.u[2] = *(const unsigned int*)(p + 4);
                r.u[3] = *(const unsigned int*)(p + 6);
                bf[nt] = r.v;
            }
            #pragma unroll
            for (int mt = 0; mt < 4; mt++)
                #pragma unroll
                for (int nt = 0; nt < 4; nt++)
                    acc[mt][nt] = __builtin_amdgcn_mfma_f32_16x16x32_bf16(
                        af[mt], bf[nt], acc[mt][nt], 0, 0, 0);
        }
        __syncthreads();
    }

    // ---- epilogue: bias add, store proj, fused pooled partials ----
    float pv[4];
    #pragma unroll
    for (int nt = 0; nt < 4; nt++)
        pv[nt] = preds[(size_t)b * HWD + l0 + wn * 64 + nt * 16 + ln];

    #pragma unroll
    for (int mt = 0; mt < 4; mt++) {
        #pragma unroll
        for (int r = 0; r < 4; r++) {
            int o = o0 + wm * 64 + mt * 16 + quad * 4 + r;
            float bv = bias[o];
            float* op = out + ((size_t)b * 512 + o) * HWD + l0 + wn * 64;
            float psum = 0.f;
            #pragma unroll
            for (int nt = 0; nt < 4; nt++) {
                float val = acc[mt][nt][r] + bv;
                op[nt * 16 + ln] = val;
                psum += val * pv[nt];
            }
            #pragma unroll
            for (int off = 1; off < 16; off <<= 1)
                psum += __shfl_xor(psum, off, 64);
            if (ln == 0)
                atomicAdd(&pooled[(size_t)b * CH_OUT + o], psum);
        }
    }
}

// ---------------------------------------------------------------------------
// Kernel 2: sequential codebook update (one block; memory fits in LDS).
// 1024 threads = 16 waves: sims phase strides p += 16 (<=2 rounds vs <=8),
// per-slot dot expression + shfl tree UNCHANGED -> bitwise-identical sims.
// Channel-parallel phases (load/update/norm) guarded to t < 256.
// ---------------------------------------------------------------------------
__global__ __launch_bounds__(1024) void k2_mem_update(
    const float* __restrict__ pooled, const int* __restrict__ epoch_p,
    float* __restrict__ mem_out, int* __restrict__ ptr_out)
{
    __shared__ float mem[MAXSLOT][256];
    __shared__ float xs[256];
    __shared__ float norms2[MAXSLOT];
    __shared__ float sims[MAXSLOT];
    __shared__ float red[4];
    __shared__ float xnorm2_s;
    __shared__ int ptr_s, row_s, ema_s;

    const int t = threadIdx.x;
    const int lane = t & 63, wid = t >> 6;   // wid 0..15

    if (t < 256)
        for (int r = 0; r < MAXSLOT; r++) mem[r][t] = 0.f;
    if (t < MAXSLOT) norms2[t] = 0.f;
    if (t == 0) ptr_s = 0;

    double thr_d = ((double)(*epoch_p)) / 10.0 - 2.0;
    thr_d = thr_d * 0.4 / 13.0 + 0.3;
    const float thr = (float)thr_d;
    __syncthreads();

    for (int bi = 0; bi < BATCH; bi++) {
        if (t < 256) {
            float x = pooled[(size_t)bi * 256 + t] * (1.0f / 4096.0f);
            xs[t] = x;
            float s = x * x;
            #pragma unroll
            for (int off = 32; off >= 1; off >>= 1) s += __shfl_xor(s, off, 64);
            if (lane == 0) red[wid] = s;
        }
        __syncthreads();
        if (t == 0) xnorm2_s = red[0] + red[1] + red[2] + red[3];
        __syncthreads();

        const int P = ptr_s;
        const float xn = sqrtf(xnorm2_s);
        for (int p = wid; p < P; p += 16) {
            float d = mem[p][lane]       * xs[lane]
                    + mem[p][lane + 64]  * xs[lane + 64]
                    + mem[p][lane + 128] * xs[lane + 128]
                    + mem[p][lane + 192] * xs[lane + 192];
            #pragma unroll
            for (int off = 32; off >= 1; off >>= 1) d += __shfl_xor(d, off, 64);
            if (lane == 0) {
                float nrm = sqrtf(norms2[p]);
                if (nrm == 0.f) nrm = 1.f;
                sims[p] = d / (nrm * xn);
            }
        }
        __syncthreads();

        if (wid == 0) {
            float v = (lane < P) ? sims[lane] : -INFINITY;
            int idx = lane;
            #pragma unroll
            for (int off = 32; off >= 1; off >>= 1) {
                float ov = __shfl_down(v, off, 64);
                int   oi = __shfl_down(idx, off, 64);
                if (ov > v || (ov == v && oi < idx)) { v = ov; idx = oi; }
            }
            if (lane == 0) {
                int ema = (P > 0 && v >= thr) ? 1 : 0;
                ema_s = ema;
                row_s = ema ? idx : P;
                if (!ema) ptr_s = P + 1;
            }
        }
        __syncthreads();

        const int r = row_s;
        if (t < 256) {
            float nv = ema_s ? (mem[r][t] * 0.9f + 0.1f * xs[t]) : xs[t];
            mem[r][t] = nv;
            float s2 = nv * nv;
            #pragma unroll
            for (int off = 32; off >= 1; off >>= 1) s2 += __shfl_xor(s2, off, 64);
            if (lane == 0) red[wid] = s2;
        }
        __syncthreads();
        if (t == 0) norms2[r] = red[0] + red[1] + red[2] + red[3];
        __syncthreads();
    }

    if (t < 256)
        for (int r = 0; r < MAXSLOT; r++) mem_out[(size_t)r * 256 + t] = mem[r][t];
    if (t == 0) ptr_out[0] = ptr_s;
}

// ---------------------------------------------------------------------------
// Kernel 3: memory cross-attention, MFMA for both GEMM phases.
//   phase A: logits[32p,128l] = mem[32,256] @ proj[256,128]  (bf16 MFMA, 8 K-steps)
//   phase B: softmax over slots per column (threads 0..127), fp32, unchanged
//   phase C: aug[256c,128l] = memT[256,32] @ attn[32,128]    (bf16 MFMA, 1 K-step)
// Fragment geometry (A pitch-40 reads, B pitch-42 union reads, C-layout) is
// copied verbatim from harness-proven k1. memS buffer (20.5KB) holds memA
// (K-chunked [8][32][40]) for phase A, then is overwritten with memT
// ([256][40]) for phase C. attn rows p>=P are zeroed at bf16 conversion
// (== reference -inf masking). LDS 48.1KB -> 3 blocks/CU.
// ---------------------------------------------------------------------------
#define PT  132  // attnL pitch (fp32 logits 32p x 128l)
#define PMS 40   // memS row pitch (shorts)
#define PBS 42   // Bs row pitch (shorts)
__global__ __launch_bounds__(256) void k3_attention(
    const float* __restrict__ mem_g, const int* __restrict__ ptr_g,
    float* __restrict__ out)
{
    __shared__ __align__(16) unsigned short memS[10240];     // 20480 B
    __shared__ __align__(16) unsigned short Bs[128 * PBS];   // 10752 B
    __shared__ __align__(16) float attnL[MAXSLOT * PT];      // 16896 B

    const int t = threadIdx.x;
    const int lt = blockIdx.x, b = blockIdx.y;
    const int l0 = lt * 128;
    const int P = ptr_g[0];

    const int lane = t & 63, wid = t >> 6;
    const int wm = wid & 1, wn = wid >> 1;       // wave 2x2 grid
    const int ln = lane & 15, quad = lane >> 4;

    // ---- stage memA: mem_g[32p][256c] fp32 -> memS[k][32p][40] bf16 ----
    #pragma unroll
    for (int q = 0; q < 16; q++) {
        int idx = t + 256 * q;                 // 0..4095
        int p = idx >> 7, cp = idx & 127;      // c = 2*cp
        float2 v = *(const float2*)(mem_g + (size_t)p * 256 + cp * 2);
        *(unsigned int*)(memS + (cp >> 4) * (32 * PMS) + p * PMS + (cp & 15) * 2)
            = pk_bf16(v.x, v.y);
    }

    const float* Pb = out + (size_t)b * 512 * HWD + l0;
    const int l4 = t & 31;      // staging: l = l4*4 + i
    const int cg = t >> 5;      // staging: c = cg*4 + j

    floatx4 accA[4];
    #pragma unroll
    for (int nt = 0; nt < 4; nt++) accA[nt] = (floatx4){0.f, 0.f, 0.f, 0.f};

    // ---- phase A K-loop: 8 chunks of 32 c ----
    for (int k0 = 0; k0 < 8; k0++) {
        // stage proj chunk [32c][128l] -> Bs[l][c] bf16 (k1's proven stage-B)
        float4 f0 = *(const float4*)(Pb + (size_t)(k0 * 32 + cg * 4 + 0) * HWD + l4 * 4);
        float4 f1 = *(const float4*)(Pb + (size_t)(k0 * 32 + cg * 4 + 1) * HWD + l4 * 4);
        float4 f2 = *(const float4*)(Pb + (size_t)(k0 * 32 + cg * 4 + 2) * HWD + l4 * 4);
        float4 f3 = *(const float4*)(Pb + (size_t)(k0 * 32 + cg * 4 + 3) * HWD + l4 * 4);
        {
            const float v0[4] = {f0.x, f0.y, f0.z, f0.w};
            const float v1[4] = {f1.x, f1.y, f1.z, f1.w};
            const float v2[4] = {f2.x, f2.y, f2.z, f2.w};
            const float v3[4] = {f3.x, f3.y, f3.z, f3.w};
            #pragma unroll
            for (int i = 0; i < 4; i++) {
                unsigned short* row = Bs + (l4 * 4 + i) * PBS + cg * 4;
                *(unsigned int*)(row)     = pk_bf16(v0[i], v1[i]);
                *(unsigned int*)(row + 2) = pk_bf16(v2[i], v3[i]);
            }
        }
        __syncthreads();

        // A-frag: mem row (wm*16+ln), k-chunk k0, shorts quad*8..+7
        short8 af = *(const short8*)(memS + k0 * (32 * PMS) + (wm * 16 + ln) * PMS + quad * 8);
        short8 bf[4];
        #pragma unroll
        for (int nt = 0; nt < 4; nt++) {
            const unsigned short* p = Bs + (wn * 64 + nt * 16 + ln) * PBS + quad * 8;
            union { short8 v; unsigned int u[4]; } r;
            r.u[0] = *(const unsigned int*)(p);
            r.u[1] = *(const unsigned int*)(p + 2);
            r.u[2] = *(const unsigned int*)(p + 4);
            r.u[3] = *(const unsigned int*)(p + 6);
            bf[nt] = r.v;
        }
        #pragma unroll
        for (int nt = 0; nt < 4; nt++)
            accA[nt] = __builtin_amdgcn_mfma_f32_16x16x32_bf16(af, bf[nt], accA[nt], 0, 0, 0);
        __syncthreads();
    }

    // ---- logits to attnL (C-frag: row p = wm*16+quad*4+r, col l) ----
    #pragma unroll
    for (int nt = 0; nt < 4; nt++)
        #pragma unroll
        for (int r = 0; r < 4; r++)
            attnL[(wm * 16 + quad * 4 + r) * PT + wn * 64 + nt * 16 + ln] = accA[nt][r];
    __syncthreads();

    // ---- phase B: softmax over valid slots, per column ----
    if (t < 128) {
        float m = -INFINITY;
        for (int p = 0; p < P; p++) m = fmaxf(m, attnL[p * PT + t]);
        float d = 0.f;
        for (int p = 0; p < P; p++) {
            float e = __expf(attnL[p * PT + t] - m);
            attnL[p * PT + t] = e;
            d += e;
        }
        float inv = 1.f / d;
        for (int p = 0; p < P; p++) attnL[p * PT + t] *= inv;
    }
    __syncthreads();

    // ---- convert attn -> Bs as attn^T bf16 [l][p], zero p >= P ----
    if (t < 128) {
        #pragma unroll
        for (int pp = 0; pp < 16; pp++) {
            float a = (2 * pp     < P) ? attnL[(2 * pp) * PT + t]     : 0.f;
            float c = (2 * pp + 1 < P) ? attnL[(2 * pp + 1) * PT + t] : 0.f;
            *(unsigned int*)(Bs + t * PBS + pp * 2) = pk_bf16(a, c);
        }
    }
    // ---- stage memT: mem_g[32p][256c] -> memS[256c][40] bf16 (p pairs) ----
    #pragma unroll
    for (int q = 0; q < 16; q++) {
        int idx = t + 256 * q;                 // 0..4095
        int c = idx & 255, pp = idx >> 8;      // p = 2*pp
        float va = mem_g[(size_t)(2 * pp)     * 256 + c];
        float vb = mem_g[(size_t)(2 * pp + 1) * 256 + c];
        *(unsigned int*)(memS + c * PMS + pp * 2) = pk_bf16(va, vb);
    }
    __syncthreads();

    // ---- phase C: aug = memT @ attn, one K=32 MFMA step, 2 c-passes ----
    short8 bfc[4];
    #pragma unroll
    for (int nt = 0; nt < 4; nt++) {
        const unsigned short* p = Bs + (wn * 64 + nt * 16 + ln) * PBS + quad * 8;
        union { short8 v; unsigned int u[4]; } r;
        r.u[0] = *(const unsigned int*)(p);
        r.u[1] = *(const unsigned int*)(p + 2);
        r.u[2] = *(const unsigned int*)(p + 4);
        r.u[3] = *(const unsigned int*)(p + 6);
        bfc[nt] = r.v;
    }
    const floatx4 zf = (floatx4){0.f, 0.f, 0.f, 0.f};
    for (int h = 0; h < 2; h++) {
        const int cbase = h * 128 + wm * 64;
        short8 afc[4];
        #pragma unroll
        for (int ct = 0; ct < 4; ct++)
            afc[ct] = *(const short8*)(memS + (cbase + ct * 16 + ln) * PMS + quad * 8);
        #pragma unroll
        for (int ct = 0; ct < 4; ct++) {
            floatx4 accC[4];
            #pragma unroll
            for (int nt = 0; nt < 4; nt++)
                accC[nt] = __builtin_amdgcn_mfma_f32_16x16x32_bf16(afc[ct], bfc[nt], zf, 0, 0, 0);
            #pragma unroll
            for (int r = 0; r < 4; r++) {
                int c = cbase + ct * 16 + quad * 4 + r;
                float* op = out + ((size_t)b * 512 + 256 + c) * HWD + l0 + wn * 64;
                #pragma unroll
                for (int nt = 0; nt < 4; nt++)
                    op[nt * 16 + ln] = accC[nt][r];
            }
        }
    }
}

// ---------------------------------------------------------------------------
extern "C" void kernel_launch(void* const* d_in, const int* in_sizes, int n_in,
                              void* d_out, int out_size, void* d_ws, size_t ws_size,
                              hipStream_t stream) {
    const float* feats = (const float*)d_in[0];
    const float* preds = (const float*)d_in[1];
    const float* W     = (const float*)d_in[2];
    const float* bias  = (const float*)d_in[3];
    const int*   epoch = (const int*)d_in[4];
    float* out = (float*)d_out;

    float* ws     = (float*)d_ws;
    float* pooled = ws;              // 32*256 floats (accumulated via atomics)
    float* mem_g  = ws + 8192;       // 32*256 floats
    int*   ptr_g  = (int*)(ws + 16384);

    hipMemsetAsync(pooled, 0, 8192 * sizeof(float), stream);

    k1_proj_gemm<<<dim3(2048), 256, 0, stream>>>(feats, preds, W, bias, out, pooled);
    k2_mem_update<<<1, 1024, 0, stream>>>(pooled, epoch, mem_g, ptr_g);
    k3_attention<<<dim3(32, 32), 256, 0, stream>>>(mem_g, ptr_g, out);
}

// Round 10
// 600.944 us; speedup vs baseline: 1.0393x; 1.0393x over previous
//
#include <hip/hip_runtime.h>
#include <math.h>

#define CH_IN   512
#define CH_OUT  256
#define HWD     4096
#define BATCH   32
#define MAXSLOT 32   // ptr can never exceed 32: at most one append per batch step

typedef __attribute__((ext_vector_type(8))) short short8;
typedef __attribute__((ext_vector_type(4))) float floatx4;

// fp32 -> bf16 RNE, packed pair into one uint (low = a, high = b)
__device__ __forceinline__ unsigned int pk_bf16(float a, float b) {
    unsigned int ua = __float_as_uint(a);
    ua += 0x7fffu + ((ua >> 16) & 1u);
    unsigned int ub = __float_as_uint(b);
    ub += 0x7fffu + ((ub >> 16) & 1u);
    return (ua >> 16) | (ub & 0xffff0000u);
}

// ---------------------------------------------------------------------------
// Kernel 1: proj = W @ feats + b  via bf16 MFMA 16x16x32, fp32 accumulate.
// BK=32 geometry reverted to the harness-proven 592.8µs version (PA=40/PB=42,
// plain __launch_bounds__(256) -- the (256,4) pin at BK=64 squeezed regalloc
// to 64 VGPR and serialized staging: 185µs, MfmaUtil 7%).
// NEW: T14 register prefetch -- pack iter-k regs->LDS, barrier, ISSUE iter-k+1
// global loads, then MFMA. HBM latency hides under the MFMA block instead of
// being fully exposed once per iteration. Pack/MFMA order unchanged ->
// bitwise-identical output.
// Grid: 2048 linear, XCD-aware decode (ot-pair adjacent on one XCD).
// Fused: pooled[b][o] += sum_l proj*preds (mean applied in k2).
// ---------------------------------------------------------------------------
#define PA 40
#define PB 42
__global__ __launch_bounds__(256) void k1_proj_gemm(
    const float* __restrict__ feats, const float* __restrict__ preds,
    const float* __restrict__ W, const float* __restrict__ bias,
    float* __restrict__ out, float* __restrict__ pooled)
{
    __shared__ __align__(16) unsigned short As[128 * PA];
    __shared__ __align__(16) unsigned short Bs[128 * PB];

    const int t  = threadIdx.x;
    // XCD-aware decode: xcd = bid%8 (round-robin mapping), 256 slots per XCD.
    const int bid  = blockIdx.x;
    const int xcd  = bid & 7;
    const int slot = bid >> 3;                 // 0..255
    const int tile = xcd * 128 + (slot >> 1);  // 0..1023
    const int ot   = slot & 1;
    const int lt   = tile & 31;
    const int b    = tile >> 5;

    const int l0 = lt * 128, o0 = ot * 128;
    const int lane = t & 63, wid = t >> 6;
    const int wm = wid & 1, wn = wid >> 1;       // wave 2x2 grid
    const int ln = lane & 15, quad = lane >> 4;

    floatx4 acc[4][4];
    #pragma unroll
    for (int i = 0; i < 4; i++)
        #pragma unroll
        for (int j = 0; j < 4; j++) acc[i][j] = (floatx4){0.f, 0.f, 0.f, 0.f};

    const float* Wb = W + (size_t)o0 * CH_IN;
    const float* Fb = feats + (size_t)b * CH_IN * HWD + l0;

    // stage-A mapping: o = (t>>3) + 32q, c4 = t&7  (identical to proven idx math)
    const int oA = t >> 3, c4 = t & 7;
    // stage-B mapping: thread owns 4c x 4l micro-block
    const int l4 = t & 31;      // l = l4*4 + i
    const int cg = t >> 5;      // c = cg*4 + j

    // ---- prologue: prefetch K-chunk 0 into registers ----
    float4 wst[4], fst[4];
    #pragma unroll
    for (int q = 0; q < 4; q++)
        wst[q] = *(const float4*)(Wb + (size_t)(oA + 32 * q) * CH_IN + c4 * 4);
    #pragma unroll
    for (int j = 0; j < 4; j++)
        fst[j] = *(const float4*)(Fb + (size_t)(cg * 4 + j) * HWD + l4 * 4);

    #pragma unroll 1
    for (int k0 = 0; k0 < CH_IN; k0 += 32) {
        // ---- pack staged regs -> LDS (same order/values as proven version) ----
        #pragma unroll
        for (int q = 0; q < 4; q++) {
            unsigned int u0 = pk_bf16(wst[q].x, wst[q].y);
            unsigned int u1 = pk_bf16(wst[q].z, wst[q].w);
            *(uint2*)(As + (oA + 32 * q) * PA + c4 * 4) = make_uint2(u0, u1);
        }
        {
            const float v0[4] = {fst[0].x, fst[0].y, fst[0].z, fst[0].w};
            const float v1[4] = {fst[1].x, fst[1].y, fst[1].z, fst[1].w};
            const float v2[4] = {fst[2].x, fst[2].y, fst[2].z, fst[2].w};
            const float v3[4] = {fst[3].x, fst[3].y, fst[3].z, fst[3].w};
            #pragma unroll
            for (int i = 0; i < 4; i++) {
                unsigned short* row = Bs + (l4 * 4 + i) * PB + cg * 4;
                *(unsigned int*)(row)     = pk_bf16(v0[i], v1[i]);
                *(unsigned int*)(row + 2) = pk_bf16(v2[i], v3[i]);
            }
        }
        __syncthreads();

        // ---- T14: issue next K-chunk loads NOW; consumed next iteration ----
        if (k0 + 32 < CH_IN) {
            #pragma unroll
            for (int q = 0; q < 4; q++)
                wst[q] = *(const float4*)(Wb + (size_t)(oA + 32 * q) * CH_IN
                                          + (k0 + 32) + c4 * 4);
            #pragma unroll
            for (int j = 0; j < 4; j++)
                fst[j] = *(const float4*)(Fb + (size_t)(k0 + 32 + cg * 4 + j) * HWD
                                          + l4 * 4);
        }

        // ---- fragments + MFMA (verbatim proven geometry) ----
        short8 af[4], bf[4];
        #pragma unroll
        for (int mt = 0; mt < 4; mt++) {
            int row = wm * 64 + mt * 16 + ln;
            af[mt] = *(const short8*)(As + row * PA + quad * 8);
        }
        #pragma unroll
        for (int nt = 0; nt < 4; nt++) {
            int row = wn * 64 + nt * 16 + ln;
            const unsigned short* p = Bs + row * PB + quad * 8;
            union { short8 v; unsigned int u[4]; } r;
            r.u[0] = *(const unsigned int*)(p);
            r.u[1] = *(const unsigned int*)(p + 2);
            r.u[2] = *(const unsigned int*)(p + 4);
            r.u[3] = *(const unsigned int*)(p + 6);
            bf[nt] = r.v;
        }
        #pragma unroll
        for (int mt = 0; mt < 4; mt++)
            #pragma unroll
            for (int nt = 0; nt < 4; nt++)
                acc[mt][nt] = __builtin_amdgcn_mfma_f32_16x16x32_bf16(
                    af[mt], bf[nt], acc[mt][nt], 0, 0, 0);
        __syncthreads();
    }

    // ---- epilogue: bias add, store proj, fused pooled partials ----
    float pv[4];
    #pragma unroll
    for (int nt = 0; nt < 4; nt++)
        pv[nt] = preds[(size_t)b * HWD + l0 + wn * 64 + nt * 16 + ln];

    #pragma unroll
    for (int mt = 0; mt < 4; mt++) {
        #pragma unroll
        for (int r = 0; r < 4; r++) {
            int o = o0 + wm * 64 + mt * 16 + quad * 4 + r;
            float bv = bias[o];
            float* op = out + ((size_t)b * 512 + o) * HWD + l0 + wn * 64;
            float psum = 0.f;
            #pragma unroll
            for (int nt = 0; nt < 4; nt++) {
                float val = acc[mt][nt][r] + bv;
                op[nt * 16 + ln] = val;
                psum += val * pv[nt];
            }
            #pragma unroll
            for (int off = 1; off < 16; off <<= 1)
                psum += __shfl_xor(psum, off, 64);
            if (ln == 0)
                atomicAdd(&pooled[(size_t)b * CH_OUT + o], psum);
        }
    }
}

// ---------------------------------------------------------------------------
// Kernel 2: sequential codebook update (one block; memory fits in LDS).
// 1024 threads = 16 waves: sims phase strides p += 16 (<=2 rounds vs <=8),
// per-slot dot expression + shfl tree UNCHANGED -> bitwise-identical sims.
// Channel-parallel phases (load/update/norm) guarded to t < 256.
// ---------------------------------------------------------------------------
__global__ __launch_bounds__(1024) void k2_mem_update(
    const float* __restrict__ pooled, const int* __restrict__ epoch_p,
    float* __restrict__ mem_out, int* __restrict__ ptr_out)
{
    __shared__ float mem[MAXSLOT][256];
    __shared__ float xs[256];
    __shared__ float norms2[MAXSLOT];
    __shared__ float sims[MAXSLOT];
    __shared__ float red[4];
    __shared__ float xnorm2_s;
    __shared__ int ptr_s, row_s, ema_s;

    const int t = threadIdx.x;
    const int lane = t & 63, wid = t >> 6;   // wid 0..15

    if (t < 256)
        for (int r = 0; r < MAXSLOT; r++) mem[r][t] = 0.f;
    if (t < MAXSLOT) norms2[t] = 0.f;
    if (t == 0) ptr_s = 0;

    double thr_d = ((double)(*epoch_p)) / 10.0 - 2.0;
    thr_d = thr_d * 0.4 / 13.0 + 0.3;
    const float thr = (float)thr_d;
    __syncthreads();

    for (int bi = 0; bi < BATCH; bi++) {
        if (t < 256) {
            float x = pooled[(size_t)bi * 256 + t] * (1.0f / 4096.0f);
            xs[t] = x;
            float s = x * x;
            #pragma unroll
            for (int off = 32; off >= 1; off >>= 1) s += __shfl_xor(s, off, 64);
            if (lane == 0) red[wid] = s;
        }
        __syncthreads();
        if (t == 0) xnorm2_s = red[0] + red[1] + red[2] + red[3];
        __syncthreads();

        const int P = ptr_s;
        const float xn = sqrtf(xnorm2_s);
        for (int p = wid; p < P; p += 16) {
            float d = mem[p][lane]       * xs[lane]
                    + mem[p][lane + 64]  * xs[lane + 64]
                    + mem[p][lane + 128] * xs[lane + 128]
                    + mem[p][lane + 192] * xs[lane + 192];
            #pragma unroll
            for (int off = 32; off >= 1; off >>= 1) d += __shfl_xor(d, off, 64);
            if (lane == 0) {
                float nrm = sqrtf(norms2[p]);
                if (nrm == 0.f) nrm = 1.f;
                sims[p] = d / (nrm * xn);
            }
        }
        __syncthreads();

        if (wid == 0) {
            float v = (lane < P) ? sims[lane] : -INFINITY;
            int idx = lane;
            #pragma unroll
            for (int off = 32; off >= 1; off >>= 1) {
                float ov = __shfl_down(v, off, 64);
                int   oi = __shfl_down(idx, off, 64);
                if (ov > v || (ov == v && oi < idx)) { v = ov; idx = oi; }
            }
            if (lane == 0) {
                int ema = (P > 0 && v >= thr) ? 1 : 0;
                ema_s = ema;
                row_s = ema ? idx : P;
                if (!ema) ptr_s = P + 1;
            }
        }
        __syncthreads();

        const int r = row_s;
        if (t < 256) {
            float nv = ema_s ? (mem[r][t] * 0.9f + 0.1f * xs[t]) : xs[t];
            mem[r][t] = nv;
            float s2 = nv * nv;
            #pragma unroll
            for (int off = 32; off >= 1; off >>= 1) s2 += __shfl_xor(s2, off, 64);
            if (lane == 0) red[wid] = s2;
        }
        __syncthreads();
        if (t == 0) norms2[r] = red[0] + red[1] + red[2] + red[3];
        __syncthreads();
    }

    if (t < 256)
        for (int r = 0; r < MAXSLOT; r++) mem_out[(size_t)r * 256 + t] = mem[r][t];
    if (t == 0) ptr_out[0] = ptr_s;
}

// ---------------------------------------------------------------------------
// Kernel 3: memory cross-attention, MFMA for both GEMM phases.
//   phase A: logits[32p,128l] = mem[32,256] @ proj[256,128]  (bf16 MFMA, 8 K-steps)
//   phase B: softmax over slots per column (threads 0..127), fp32, unchanged
//   phase C: aug[256c,128l] = memT[256,32] @ attn[32,128]    (bf16 MFMA, 1 K-step)
// Fragment geometry (A pitch-40 reads, B pitch-42 union reads, C-layout) is
// copied verbatim from harness-proven k1. memS buffer (20.5KB) holds memA
// (K-chunked [8][32][40]) for phase A, then is overwritten with memT
// ([256][40]) for phase C. attn rows p>=P are zeroed at bf16 conversion
// (== reference -inf masking). LDS 48.1KB -> 3 blocks/CU.
// ---------------------------------------------------------------------------
#define PT  132  // attnL pitch (fp32 logits 32p x 128l)
#define PMS 40   // memS row pitch (shorts)
#define PBS 42   // Bs row pitch (shorts)
__global__ __launch_bounds__(256) void k3_attention(
    const float* __restrict__ mem_g, const int* __restrict__ ptr_g,
    float* __restrict__ out)
{
    __shared__ __align__(16) unsigned short memS[10240];     // 20480 B
    __shared__ __align__(16) unsigned short Bs[128 * PBS];   // 10752 B
    __shared__ __align__(16) float attnL[MAXSLOT * PT];      // 16896 B

    const int t = threadIdx.x;
    const int lt = blockIdx.x, b = blockIdx.y;
    const int l0 = lt * 128;
    const int P = ptr_g[0];

    const int lane = t & 63, wid = t >> 6;
    const int wm = wid & 1, wn = wid >> 1;       // wave 2x2 grid
    const int ln = lane & 15, quad = lane >> 4;

    // ---- stage memA: mem_g[32p][256c] fp32 -> memS[k][32p][40] bf16 ----
    #pragma unroll
    for (int q = 0; q < 16; q++) {
        int idx = t + 256 * q;                 // 0..4095
        int p = idx >> 7, cp = idx & 127;      // c = 2*cp
        float2 v = *(const float2*)(mem_g + (size_t)p * 256 + cp * 2);
        *(unsigned int*)(memS + (cp >> 4) * (32 * PMS) + p * PMS + (cp & 15) * 2)
            = pk_bf16(v.x, v.y);
    }

    const float* Pb = out + (size_t)b * 512 * HWD + l0;
    const int l4 = t & 31;      // staging: l = l4*4 + i
    const int cg = t >> 5;      // staging: c = cg*4 + j

    floatx4 accA[4];
    #pragma unroll
    for (int nt = 0; nt < 4; nt++) accA[nt] = (floatx4){0.f, 0.f, 0.f, 0.f};

    // ---- phase A K-loop: 8 chunks of 32 c ----
    for (int k0 = 0; k0 < 8; k0++) {
        // stage proj chunk [32c][128l] -> Bs[l][c] bf16 (k1's proven stage-B)
        float4 f0 = *(const float4*)(Pb + (size_t)(k0 * 32 + cg * 4 + 0) * HWD + l4 * 4);
        float4 f1 = *(const float4*)(Pb + (size_t)(k0 * 32 + cg * 4 + 1) * HWD + l4 * 4);
        float4 f2 = *(const float4*)(Pb + (size_t)(k0 * 32 + cg * 4 + 2) * HWD + l4 * 4);
        float4 f3 = *(const float4*)(Pb + (size_t)(k0 * 32 + cg * 4 + 3) * HWD + l4 * 4);
        {
            const float v0[4] = {f0.x, f0.y, f0.z, f0.w};
            const float v1[4] = {f1.x, f1.y, f1.z, f1.w};
            const float v2[4] = {f2.x, f2.y, f2.z, f2.w};
            const float v3[4] = {f3.x, f3.y, f3.z, f3.w};
            #pragma unroll
            for (int i = 0; i < 4; i++) {
                unsigned short* row = Bs + (l4 * 4 + i) * PBS + cg * 4;
                *(unsigned int*)(row)     = pk_bf16(v0[i], v1[i]);
                *(unsigned int*)(row + 2) = pk_bf16(v2[i], v3[i]);
            }
        }
        __syncthreads();

        // A-frag: mem row (wm*16+ln), k-chunk k0, shorts quad*8..+7
        short8 af = *(const short8*)(memS + k0 * (32 * PMS) + (wm * 16 + ln) * PMS + quad * 8);
        short8 bf[4];
        #pragma unroll
        for (int nt = 0; nt < 4; nt++) {
            const unsigned short* p = Bs + (wn * 64 + nt * 16 + ln) * PBS + quad * 8;
            union { short8 v; unsigned int u[4]; } r;
            r.u[0] = *(const unsigned int*)(p);
            r.u[1] = *(const unsigned int*)(p + 2);
            r.u[2] = *(const unsigned int*)(p + 4);
            r.u[3] = *(const unsigned int*)(p + 6);
            bf[nt] = r.v;
        }
        #pragma unroll
        for (int nt = 0; nt < 4; nt++)
            accA[nt] = __builtin_amdgcn_mfma_f32_16x16x32_bf16(af, bf[nt], accA[nt], 0, 0, 0);
        __syncthreads();
    }

    // ---- logits to attnL (C-frag: row p = wm*16+quad*4+r, col l) ----
    #pragma unroll
    for (int nt = 0; nt < 4; nt++)
        #pragma unroll
        for (int r = 0; r < 4; r++)
            attnL[(wm * 16 + quad * 4 + r) * PT + wn * 64 + nt * 16 + ln] = accA[nt][r];
    __syncthreads();

    // ---- phase B: softmax over valid slots, per column ----
    if (t < 128) {
        float m = -INFINITY;
        for (int p = 0; p < P; p++) m = fmaxf(m, attnL[p * PT + t]);
        float d = 0.f;
        for (int p = 0; p < P; p++) {
            float e = __expf(attnL[p * PT + t] - m);
            attnL[p * PT + t] = e;
            d += e;
        }
        float inv = 1.f / d;
        for (int p = 0; p < P; p++) attnL[p * PT + t] *= inv;
    }
    __syncthreads();

    // ---- convert attn -> Bs as attn^T bf16 [l][p], zero p >= P ----
    if (t < 128) {
        #pragma unroll
        for (int pp = 0; pp < 16; pp++) {
            float a = (2 * pp     < P) ? attnL[(2 * pp) * PT + t]     : 0.f;
            float c = (2 * pp + 1 < P) ? attnL[(2 * pp + 1) * PT + t] : 0.f;
            *(unsigned int*)(Bs + t * PBS + pp * 2) = pk_bf16(a, c);
        }
    }
    // ---- stage memT: mem_g[32p][256c] -> memS[256c][40] bf16 (p pairs) ----
    #pragma unroll
    for (int q = 0; q < 16; q++) {
        int idx = t + 256 * q;                 // 0..4095
        int c = idx & 255, pp = idx >> 8;      // p = 2*pp
        float va = mem_g[(size_t)(2 * pp)     * 256 + c];
        float vb = mem_g[(size_t)(2 * pp + 1) * 256 + c];
        *(unsigned int*)(memS + c * PMS + pp * 2) = pk_bf16(va, vb);
    }
    __syncthreads();

    // ---- phase C: aug = memT @ attn, one K=32 MFMA step, 2 c-passes ----
    short8 bfc[4];
    #pragma unroll
    for (int nt = 0; nt < 4; nt++) {
        const unsigned short* p = Bs + (wn * 64 + nt * 16 + ln) * PBS + quad * 8;
        union { short8 v; unsigned int u[4]; } r;
        r.u[0] = *(const unsigned int*)(p);
        r.u[1] = *(const unsigned int*)(p + 2);
        r.u[2] = *(const unsigned int*)(p + 4);
        r.u[3] = *(const unsigned int*)(p + 6);
        bfc[nt] = r.v;
    }
    const floatx4 zf = (floatx4){0.f, 0.f, 0.f, 0.f};
    for (int h = 0; h < 2; h++) {
        const int cbase = h * 128 + wm * 64;
        short8 afc[4];
        #pragma unroll
        for (int ct = 0; ct < 4; ct++)
            afc[ct] = *(const short8*)(memS + (cbase + ct * 16 + ln) * PMS + quad * 8);
        #pragma unroll
        for (int ct = 0; ct < 4; ct++) {
            floatx4 accC[4];
            #pragma unroll
            for (int nt = 0; nt < 4; nt++)
                accC[nt] = __builtin_amdgcn_mfma_f32_16x16x32_bf16(afc[ct], bfc[nt], zf, 0, 0, 0);
            #pragma unroll
            for (int r = 0; r < 4; r++) {
                int c = cbase + ct * 16 + quad * 4 + r;
                float* op = out + ((size_t)b * 512 + 256 + c) * HWD + l0 + wn * 64;
                #pragma unroll
                for (int nt = 0; nt < 4; nt++)
                    op[nt * 16 + ln] = accC[nt][r];
            }
        }
    }
}

// ---------------------------------------------------------------------------
extern "C" void kernel_launch(void* const* d_in, const int* in_sizes, int n_in,
                              void* d_out, int out_size, void* d_ws, size_t ws_size,
                              hipStream_t stream) {
    const float* feats = (const float*)d_in[0];
    const float* preds = (const float*)d_in[1];
    const float* W     = (const float*)d_in[2];
    const float* bias  = (const float*)d_in[3];
    const int*   epoch = (const int*)d_in[4];
    float* out = (float*)d_out;

    float* ws     = (float*)d_ws;
    float* pooled = ws;              // 32*256 floats (accumulated via atomics)
    float* mem_g  = ws + 8192;       // 32*256 floats
    int*   ptr_g  = (int*)(ws + 16384);

    hipMemsetAsync(pooled, 0, 8192 * sizeof(float), stream);

    k1_proj_gemm<<<dim3(2048), 256, 0, stream>>>(feats, preds, W, bias, out, pooled);
    k2_mem_update<<<1, 1024, 0, stream>>>(pooled, epoch, mem_g, ptr_g);
    k3_attention<<<dim3(32, 32), 256, 0, stream>>>(mem_g, ptr_g, out);
}

// Round 11
// 586.763 us; speedup vs baseline: 1.0645x; 1.0242x over previous
//
#include <hip/hip_runtime.h>
#include <math.h>

#define CH_IN   512
#define CH_OUT  256
#define HWD     4096
#define BATCH   32
#define MAXSLOT 32   // ptr can never exceed 32: at most one append per batch step

typedef __attribute__((ext_vector_type(8))) short short8;
typedef __attribute__((ext_vector_type(4))) float floatx4;

// fp32 -> bf16 RNE, packed pair into one uint (low = a, high = b)
__device__ __forceinline__ unsigned int pk_bf16(float a, float b) {
    unsigned int ua = __float_as_uint(a);
    ua += 0x7fffu + ((ua >> 16) & 1u);
    unsigned int ub = __float_as_uint(b);
    ub += 0x7fffu + ((ub >> 16) & 1u);
    return (ua >> 16) | (ub & 0xffff0000u);
}

// ---------------------------------------------------------------------------
// Kernel 1: proj = W @ feats + b  via bf16 MFMA 16x16x32, fp32 accumulate.
// BK=32 proven geometry (PA=40/PB=42) + T14 register prefetch (round-10:
// 185 -> <163us). Pack/MFMA order unchanged -> bitwise-identical output.
// Grid: 2048 linear, XCD-aware decode (ot-pair adjacent on one XCD).
// Fused: pooled[b][o] += sum_l proj*preds (mean applied in k2).
// ---------------------------------------------------------------------------
#define PA 40
#define PB 42
__global__ __launch_bounds__(256) void k1_proj_gemm(
    const float* __restrict__ feats, const float* __restrict__ preds,
    const float* __restrict__ W, const float* __restrict__ bias,
    float* __restrict__ out, float* __restrict__ pooled)
{
    __shared__ __align__(16) unsigned short As[128 * PA];
    __shared__ __align__(16) unsigned short Bs[128 * PB];

    const int t  = threadIdx.x;
    const int bid  = blockIdx.x;
    const int xcd  = bid & 7;
    const int slot = bid >> 3;                 // 0..255
    const int tile = xcd * 128 + (slot >> 1);  // 0..1023
    const int ot   = slot & 1;
    const int lt   = tile & 31;
    const int b    = tile >> 5;

    const int l0 = lt * 128, o0 = ot * 128;
    const int lane = t & 63, wid = t >> 6;
    const int wm = wid & 1, wn = wid >> 1;       // wave 2x2 grid
    const int ln = lane & 15, quad = lane >> 4;

    floatx4 acc[4][4];
    #pragma unroll
    for (int i = 0; i < 4; i++)
        #pragma unroll
        for (int j = 0; j < 4; j++) acc[i][j] = (floatx4){0.f, 0.f, 0.f, 0.f};

    const float* Wb = W + (size_t)o0 * CH_IN;
    const float* Fb = feats + (size_t)b * CH_IN * HWD + l0;

    const int oA = t >> 3, c4 = t & 7;
    const int l4 = t & 31;      // l = l4*4 + i
    const int cg = t >> 5;      // c = cg*4 + j

    // ---- prologue: prefetch K-chunk 0 into registers ----
    float4 wst[4], fst[4];
    #pragma unroll
    for (int q = 0; q < 4; q++)
        wst[q] = *(const float4*)(Wb + (size_t)(oA + 32 * q) * CH_IN + c4 * 4);
    #pragma unroll
    for (int j = 0; j < 4; j++)
        fst[j] = *(const float4*)(Fb + (size_t)(cg * 4 + j) * HWD + l4 * 4);

    #pragma unroll 1
    for (int k0 = 0; k0 < CH_IN; k0 += 32) {
        #pragma unroll
        for (int q = 0; q < 4; q++) {
            unsigned int u0 = pk_bf16(wst[q].x, wst[q].y);
            unsigned int u1 = pk_bf16(wst[q].z, wst[q].w);
            *(uint2*)(As + (oA + 32 * q) * PA + c4 * 4) = make_uint2(u0, u1);
        }
        {
            const float v0[4] = {fst[0].x, fst[0].y, fst[0].z, fst[0].w};
            const float v1[4] = {fst[1].x, fst[1].y, fst[1].z, fst[1].w};
            const float v2[4] = {fst[2].x, fst[2].y, fst[2].z, fst[2].w};
            const float v3[4] = {fst[3].x, fst[3].y, fst[3].z, fst[3].w};
            #pragma unroll
            for (int i = 0; i < 4; i++) {
                unsigned short* row = Bs + (l4 * 4 + i) * PB + cg * 4;
                *(unsigned int*)(row)     = pk_bf16(v0[i], v1[i]);
                *(unsigned int*)(row + 2) = pk_bf16(v2[i], v3[i]);
            }
        }
        __syncthreads();

        if (k0 + 32 < CH_IN) {
            #pragma unroll
            for (int q = 0; q < 4; q++)
                wst[q] = *(const float4*)(Wb + (size_t)(oA + 32 * q) * CH_IN
                                          + (k0 + 32) + c4 * 4);
            #pragma unroll
            for (int j = 0; j < 4; j++)
                fst[j] = *(const float4*)(Fb + (size_t)(k0 + 32 + cg * 4 + j) * HWD
                                          + l4 * 4);
        }

        short8 af[4], bf[4];
        #pragma unroll
        for (int mt = 0; mt < 4; mt++) {
            int row = wm * 64 + mt * 16 + ln;
            af[mt] = *(const short8*)(As + row * PA + quad * 8);
        }
        #pragma unroll
        for (int nt = 0; nt < 4; nt++) {
            int row = wn * 64 + nt * 16 + ln;
            const unsigned short* p = Bs + row * PB + quad * 8;
            union { short8 v; unsigned int u[4]; } r;
            r.u[0] = *(const unsigned int*)(p);
            r.u[1] = *(const unsigned int*)(p + 2);
            r.u[2] = *(const unsigned int*)(p + 4);
            r.u[3] = *(const unsigned int*)(p + 6);
            bf[nt] = r.v;
        }
        #pragma unroll
        for (int mt = 0; mt < 4; mt++)
            #pragma unroll
            for (int nt = 0; nt < 4; nt++)
                acc[mt][nt] = __builtin_amdgcn_mfma_f32_16x16x32_bf16(
                    af[mt], bf[nt], acc[mt][nt], 0, 0, 0);
        __syncthreads();
    }

    // ---- epilogue: bias add, store proj, fused pooled partials ----
    float pv[4];
    #pragma unroll
    for (int nt = 0; nt < 4; nt++)
        pv[nt] = preds[(size_t)b * HWD + l0 + wn * 64 + nt * 16 + ln];

    #pragma unroll
    for (int mt = 0; mt < 4; mt++) {
        #pragma unroll
        for (int r = 0; r < 4; r++) {
            int o = o0 + wm * 64 + mt * 16 + quad * 4 + r;
            float bv = bias[o];
            float* op = out + ((size_t)b * 512 + o) * HWD + l0 + wn * 64;
            float psum = 0.f;
            #pragma unroll
            for (int nt = 0; nt < 4; nt++) {
                float val = acc[mt][nt][r] + bv;
                op[nt * 16 + ln] = val;
                psum += val * pv[nt];
            }
            #pragma unroll
            for (int off = 1; off < 16; off <<= 1)
                psum += __shfl_xor(psum, off, 64);
            if (ln == 0)
                atomicAdd(&pooled[(size_t)b * CH_OUT + o], psum);
        }
    }
}

// ---------------------------------------------------------------------------
// Kernel 2: sequential codebook update -- SINGLE WAVE (64 lanes), ZERO barriers.
// The 1024-thread version paid 6 __syncthreads x 32 steps plus cross-wave LDS
// round-trips (est ~140-160us, latency-bound). Within one wave all LDS RAW
// hazards are handled by in-order issue -> no barriers at all.
//  - pooled staged once to LDS (scaled 1/4096), mem + norms2 LDS-resident
//  - sims: 2 lanes per slot, each dots 128 channels (float4), shfl_xor(1) pair
//    combine -> constant-time in P
//  - argmax: EXACT same 64-wide shfl_down compare chain as passing version
//  - reduction orders (xnorm/dot/row-norm) differ from the previous version;
//    decisions flip only on ~1e-7 near-ties (pooled is already atomicAdd-order
//    nondeterministic) -- absmax canary watched.
// ---------------------------------------------------------------------------
#define PMEM 260   // padded row pitch (floats) for memL / xsAll
__global__ __launch_bounds__(64) void k2_mem_update(
    const float* __restrict__ pooled, const int* __restrict__ epoch_p,
    float* __restrict__ mem_out, int* __restrict__ ptr_out)
{
    __shared__ __align__(16) float memL[MAXSLOT * PMEM];   // 33280 B
    __shared__ __align__(16) float xsAll[BATCH * PMEM];    // 33280 B
    __shared__ float norms2[MAXSLOT];
    __shared__ float simsL[MAXSLOT];

    const int l = threadIdx.x;   // 0..63

    // init mem/norms
    for (int i = l; i < MAXSLOT * PMEM; i += 64) memL[i] = 0.f;
    if (l < MAXSLOT) norms2[l] = 0.f;

    // stage pooled -> xsAll (scaled); coalesced float4, row j per iteration
    #pragma unroll 1
    for (int j = 0; j < BATCH; j++) {
        float4 v = *(const float4*)(pooled + (size_t)j * 256 + l * 4);
        float* dst = xsAll + j * PMEM + l * 4;
        dst[0] = v.x * (1.0f / 4096.0f);
        dst[1] = v.y * (1.0f / 4096.0f);
        dst[2] = v.z * (1.0f / 4096.0f);
        dst[3] = v.w * (1.0f / 4096.0f);
    }

    double thr_d = ((double)(*epoch_p)) / 10.0 - 2.0;
    thr_d = thr_d * 0.4 / 13.0 + 0.3;
    const float thr = (float)thr_d;

    const int sp = l >> 1, half = l & 1;     // sims role: slot sp, channel half
    int ptr = 0;

    #pragma unroll 1
    for (int bi = 0; bi < BATCH; bi++) {
        const float* xs = xsAll + bi * PMEM;

        // xnorm2: lane-local 4 channels then 64-lane xor tree (all lanes get sum)
        float s = xs[l] * xs[l] + xs[l + 64] * xs[l + 64]
                + xs[l + 128] * xs[l + 128] + xs[l + 192] * xs[l + 192];
        #pragma unroll
        for (int off = 32; off >= 1; off >>= 1) s += __shfl_xor(s, off, 64);
        const float xn = sqrtf(s);

        const int P = ptr;

        // sims for ALL 32 slots in parallel (rows >= P are zero -> masked later)
        {
            const float* mrow = memL + sp * PMEM + half * 128;
            const float* xrow = xs + half * 128;
            float d = 0.f;
            #pragma unroll
            for (int i = 0; i < 32; i++) {
                float4 m  = *(const float4*)(mrow + i * 4);
                float4 xv = *(const float4*)(xrow + i * 4);
                d = fmaf(m.x, xv.x, d);
                d = fmaf(m.y, xv.y, d);
                d = fmaf(m.z, xv.z, d);
                d = fmaf(m.w, xv.w, d);
            }
            d += __shfl_xor(d, 1, 64);
            if (half == 0) {
                float nrm = sqrtf(norms2[sp]);
                if (nrm == 0.f) nrm = 1.f;
                simsL[sp] = d / (nrm * xn);
            }
        }

        // argmax: identical compare chain to the passing version
        float v = (l < P) ? simsL[l] : -INFINITY;
        int idx = l;
        #pragma unroll
        for (int off = 32; off >= 1; off >>= 1) {
            float ov = __shfl_down(v, off, 64);
            int   oi = __shfl_down(idx, off, 64);
            if (ov > v || (ov == v && oi < idx)) { v = ov; idx = oi; }
        }
        int ema = 0, row = 0;
        if (l == 0) {
            ema = (P > 0 && v >= thr) ? 1 : 0;
            row = ema ? idx : P;
        }
        ema = __shfl(ema, 0, 64);
        row = __shfl(row, 0, 64);
        if (!ema) ptr = P + 1;

        // update row + its norm2 (lane-local 4 channels, xor tree)
        float* mr = memL + row * PMEM;
        float s2 = 0.f;
        #pragma unroll
        for (int k = 0; k < 4; k++) {
            int c = l + 64 * k;
            float nv = ema ? (mr[c] * 0.9f + 0.1f * xs[c]) : xs[c];
            mr[c] = nv;
            s2 = fmaf(nv, nv, s2);
        }
        #pragma unroll
        for (int off = 32; off >= 1; off >>= 1) s2 += __shfl_xor(s2, off, 64);
        if (l == 0) norms2[row] = s2;
    }

    // writeback
    #pragma unroll 1
    for (int r = 0; r < MAXSLOT; r++) {
        float4 v = *(const float4*)(memL + r * PMEM + l * 4);
        *(float4*)(mem_out + (size_t)r * 256 + l * 4) = v;
    }
    if (l == 0) ptr_out[0] = ptr;
}

// ---------------------------------------------------------------------------
// Kernel 3: memory cross-attention, MFMA for both GEMM phases (unchanged,
// harness-verified at 592.8/600.9us totals).
// ---------------------------------------------------------------------------
#define PT  132  // attnL pitch (fp32 logits 32p x 128l)
#define PMS 40   // memS row pitch (shorts)
#define PBS 42   // Bs row pitch (shorts)
__global__ __launch_bounds__(256) void k3_attention(
    const float* __restrict__ mem_g, const int* __restrict__ ptr_g,
    float* __restrict__ out)
{
    __shared__ __align__(16) unsigned short memS[10240];     // 20480 B
    __shared__ __align__(16) unsigned short Bs[128 * PBS];   // 10752 B
    __shared__ __align__(16) float attnL[MAXSLOT * PT];      // 16896 B

    const int t = threadIdx.x;
    const int lt = blockIdx.x, b = blockIdx.y;
    const int l0 = lt * 128;
    const int P = ptr_g[0];

    const int lane = t & 63, wid = t >> 6;
    const int wm = wid & 1, wn = wid >> 1;       // wave 2x2 grid
    const int ln = lane & 15, quad = lane >> 4;

    // ---- stage memA: mem_g[32p][256c] fp32 -> memS[k][32p][40] bf16 ----
    #pragma unroll
    for (int q = 0; q < 16; q++) {
        int idx = t + 256 * q;                 // 0..4095
        int p = idx >> 7, cp = idx & 127;      // c = 2*cp
        float2 v = *(const float2*)(mem_g + (size_t)p * 256 + cp * 2);
        *(unsigned int*)(memS + (cp >> 4) * (32 * PMS) + p * PMS + (cp & 15) * 2)
            = pk_bf16(v.x, v.y);
    }

    const float* Pb = out + (size_t)b * 512 * HWD + l0;
    const int l4 = t & 31;      // staging: l = l4*4 + i
    const int cg = t >> 5;      // staging: c = cg*4 + j

    floatx4 accA[4];
    #pragma unroll
    for (int nt = 0; nt < 4; nt++) accA[nt] = (floatx4){0.f, 0.f, 0.f, 0.f};

    // ---- phase A K-loop: 8 chunks of 32 c ----
    for (int k0 = 0; k0 < 8; k0++) {
        float4 f0 = *(const float4*)(Pb + (size_t)(k0 * 32 + cg * 4 + 0) * HWD + l4 * 4);
        float4 f1 = *(const float4*)(Pb + (size_t)(k0 * 32 + cg * 4 + 1) * HWD + l4 * 4);
        float4 f2 = *(const float4*)(Pb + (size_t)(k0 * 32 + cg * 4 + 2) * HWD + l4 * 4);
        float4 f3 = *(const float4*)(Pb + (size_t)(k0 * 32 + cg * 4 + 3) * HWD + l4 * 4);
        {
            const float v0[4] = {f0.x, f0.y, f0.z, f0.w};
            const float v1[4] = {f1.x, f1.y, f1.z, f1.w};
            const float v2[4] = {f2.x, f2.y, f2.z, f2.w};
            const float v3[4] = {f3.x, f3.y, f3.z, f3.w};
            #pragma unroll
            for (int i = 0; i < 4; i++) {
                unsigned short* row = Bs + (l4 * 4 + i) * PBS + cg * 4;
                *(unsigned int*)(row)     = pk_bf16(v0[i], v1[i]);
                *(unsigned int*)(row + 2) = pk_bf16(v2[i], v3[i]);
            }
        }
        __syncthreads();

        short8 af = *(const short8*)(memS + k0 * (32 * PMS) + (wm * 16 + ln) * PMS + quad * 8);
        short8 bf[4];
        #pragma unroll
        for (int nt = 0; nt < 4; nt++) {
            const unsigned short* p = Bs + (wn * 64 + nt * 16 + ln) * PBS + quad * 8;
            union { short8 v; unsigned int u[4]; } r;
            r.u[0] = *(const unsigned int*)(p);
            r.u[1] = *(const unsigned int*)(p + 2);
            r.u[2] = *(const unsigned int*)(p + 4);
            r.u[3] = *(const unsigned int*)(p + 6);
            bf[nt] = r.v;
        }
        #pragma unroll
        for (int nt = 0; nt < 4; nt++)
            accA[nt] = __builtin_amdgcn_mfma_f32_16x16x32_bf16(af, bf[nt], accA[nt], 0, 0, 0);
        __syncthreads();
    }

    // ---- logits to attnL (C-frag: row p = wm*16+quad*4+r, col l) ----
    #pragma unroll
    for (int nt = 0; nt < 4; nt++)
        #pragma unroll
        for (int r = 0; r < 4; r++)
            attnL[(wm * 16 + quad * 4 + r) * PT + wn * 64 + nt * 16 + ln] = accA[nt][r];
    __syncthreads();

    // ---- phase B: softmax over valid slots, per column ----
    if (t < 128) {
        float m = -INFINITY;
        for (int p = 0; p < P; p++) m = fmaxf(m, attnL[p * PT + t]);
        float d = 0.f;
        for (int p = 0; p < P; p++) {
            float e = __expf(attnL[p * PT + t] - m);
            attnL[p * PT + t] = e;
            d += e;
        }
        float inv = 1.f / d;
        for (int p = 0; p < P; p++) attnL[p * PT + t] *= inv;
    }
    __syncthreads();

    // ---- convert attn -> Bs as attn^T bf16 [l][p], zero p >= P ----
    if (t < 128) {
        #pragma unroll
        for (int pp = 0; pp < 16; pp++) {
            float a = (2 * pp     < P) ? attnL[(2 * pp) * PT + t]     : 0.f;
            float c = (2 * pp + 1 < P) ? attnL[(2 * pp + 1) * PT + t] : 0.f;
            *(unsigned int*)(Bs + t * PBS + pp * 2) = pk_bf16(a, c);
        }
    }
    // ---- stage memT: mem_g[32p][256c] -> memS[256c][40] bf16 (p pairs) ----
    #pragma unroll
    for (int q = 0; q < 16; q++) {
        int idx = t + 256 * q;                 // 0..4095
        int c = idx & 255, pp = idx >> 8;      // p = 2*pp
        float va = mem_g[(size_t)(2 * pp)     * 256 + c];
        float vb = mem_g[(size_t)(2 * pp + 1) * 256 + c];
        *(unsigned int*)(memS + c * PMS + pp * 2) = pk_bf16(va, vb);
    }
    __syncthreads();

    // ---- phase C: aug = memT @ attn, one K=32 MFMA step, 2 c-passes ----
    short8 bfc[4];
    #pragma unroll
    for (int nt = 0; nt < 4; nt++) {
        const unsigned short* p = Bs + (wn * 64 + nt * 16 + ln) * PBS + quad * 8;
        union { short8 v; unsigned int u[4]; } r;
        r.u[0] = *(const unsigned int*)(p);
        r.u[1] = *(const unsigned int*)(p + 2);
        r.u[2] = *(const unsigned int*)(p + 4);
        r.u[3] = *(const unsigned int*)(p + 6);
        bfc[nt] = r.v;
    }
    const floatx4 zf = (floatx4){0.f, 0.f, 0.f, 0.f};
    for (int h = 0; h < 2; h++) {
        const int cbase = h * 128 + wm * 64;
        short8 afc[4];
        #pragma unroll
        for (int ct = 0; ct < 4; ct++)
            afc[ct] = *(const short8*)(memS + (cbase + ct * 16 + ln) * PMS + quad * 8);
        #pragma unroll
        for (int ct = 0; ct < 4; ct++) {
            floatx4 accC[4];
            #pragma unroll
            for (int nt = 0; nt < 4; nt++)
                accC[nt] = __builtin_amdgcn_mfma_f32_16x16x32_bf16(afc[ct], bfc[nt], zf, 0, 0, 0);
            #pragma unroll
            for (int r = 0; r < 4; r++) {
                int c = cbase + ct * 16 + quad * 4 + r;
                float* op = out + ((size_t)b * 512 + 256 + c) * HWD + l0 + wn * 64;
                #pragma unroll
                for (int nt = 0; nt < 4; nt++)
                    op[nt * 16 + ln] = accC[nt][r];
            }
        }
    }
}

// ---------------------------------------------------------------------------
extern "C" void kernel_launch(void* const* d_in, const int* in_sizes, int n_in,
                              void* d_out, int out_size, void* d_ws, size_t ws_size,
                              hipStream_t stream) {
    const float* feats = (const float*)d_in[0];
    const float* preds = (const float*)d_in[1];
    const float* W     = (const float*)d_in[2];
    const float* bias  = (const float*)d_in[3];
    const int*   epoch = (const int*)d_in[4];
    float* out = (float*)d_out;

    float* ws     = (float*)d_ws;
    float* pooled = ws;              // 32*256 floats (accumulated via atomics)
    float* mem_g  = ws + 8192;       // 32*256 floats
    int*   ptr_g  = (int*)(ws + 16384);

    hipMemsetAsync(pooled, 0, 8192 * sizeof(float), stream);

    k1_proj_gemm<<<dim3(2048), 256, 0, stream>>>(feats, preds, W, bias, out, pooled);
    k2_mem_update<<<1, 64, 0, stream>>>(pooled, epoch, mem_g, ptr_g);
    k3_attention<<<dim3(32, 32), 256, 0, stream>>>(mem_g, ptr_g, out);
}